// Round 4
// baseline (169.284 us; speedup 1.0000x reference)
//
#include <hip/hip_runtime.h>

// N-gram embedding mean on gfx950. One wave per word.
// Key structure: ALL row loads (up to 24, 12KB) issue before ANY accumulate,
// so each wave exposes one gather latency instead of three. Row ids pinned
// scalar (readfirstlane) -> saddr-form loads, zero VALU addressing, and the
// r!=0 padding masks are wave-uniform SGPR multiplies. Group skips on cnt
// are wave-uniform branches (no divergence, no shuffles).
#define NUM_WORDS 32768   // B*S = 16*2048
#define KMAX 24

__global__ __launch_bounds__(256) void ngram_emb_kernel(
    const int* __restrict__ word_idx,      // [B*S]
    const int* __restrict__ ngram_ids,     // [V, K]
    const int* __restrict__ ngram_counts,  // [V]
    const float* __restrict__ emb_table,   // [NG, E]
    float* __restrict__ out)               // [B*S, E]
{
    const int gtid = blockIdx.x * blockDim.x + threadIdx.x;
    const int word = gtid >> 6;            // one wave per word
    const int lane = threadIdx.x & 63;     // float2 chunk within the 512B row

    // wave-uniform scalars (full wave active -> readfirstlane safe)
    const int w   = __builtin_amdgcn_readfirstlane(word_idx[word]);
    const int cnt = ngram_counts[w];       // uniform scalar load
    const int* ids = ngram_ids + w * KMAX;

    int rr[KMAX];
#pragma unroll
    for (int k = 0; k < KMAX; ++k)
        rr[k] = __builtin_amdgcn_readfirstlane(ids[k]);

    const float2* tbl = (const float2*)emb_table;   // row stride = 64 float2

    // ---- phase 1: issue every load (uniform group skips, no accumulates) ----
    float2 v[KMAX];
#pragma unroll
    for (int j = 0; j < 8; ++j)
        v[j] = tbl[(long)rr[j] * 64 + lane];
    if (cnt > 8) {
#pragma unroll
        for (int j = 8; j < 16; ++j)
            v[j] = tbl[(long)rr[j] * 64 + lane];
    }
    if (cnt > 16) {
#pragma unroll
        for (int j = 16; j < 24; ++j)
            v[j] = tbl[(long)rr[j] * 64 + lane];
    }

    // ---- phase 2: masked accumulate (masks are wave-uniform scalars) ----
    float ax = 0.f, ay = 0.f;
#pragma unroll
    for (int j = 0; j < 8; ++j) {
        const float m = rr[j] ? 1.f : 0.f;
        ax = fmaf(m, v[j].x, ax);
        ay = fmaf(m, v[j].y, ay);
    }
    if (cnt > 8) {
#pragma unroll
        for (int j = 8; j < 16; ++j) {
            const float m = rr[j] ? 1.f : 0.f;
            ax = fmaf(m, v[j].x, ax);
            ay = fmaf(m, v[j].y, ay);
        }
    }
    if (cnt > 16) {
#pragma unroll
        for (int j = 16; j < 24; ++j) {
            const float m = rr[j] ? 1.f : 0.f;
            ax = fmaf(m, v[j].x, ax);
            ay = fmaf(m, v[j].y, ay);
        }
    }

    const float inv = 1.0f / (float)cnt;
    float2 o; o.x = ax * inv; o.y = ay * inv;
    ((float2*)out)[(long)word * 64 + lane] = o;    // 64 lanes x 8B = 512B row
}

extern "C" void kernel_launch(void* const* d_in, const int* in_sizes, int n_in,
                              void* d_out, int out_size, void* d_ws, size_t ws_size,
                              hipStream_t stream) {
    const int*   word_idx     = (const int*)d_in[0];
    const int*   ngram_ids    = (const int*)d_in[1];
    const int*   ngram_counts = (const int*)d_in[2];
    const float* emb_table    = (const float*)d_in[3];
    float*       out          = (float*)d_out;

    const int threads = 256;
    const int blocks  = (NUM_WORDS * 64) / threads;  // 8192
    ngram_emb_kernel<<<blocks, threads, 0, stream>>>(
        word_idx, ngram_ids, ngram_counts, emb_table, out);
}